// Round 1
// baseline (649.360 us; speedup 1.0000x reference)
//
#include <hip/hip_runtime.h>

using f32x4  = __attribute__((ext_vector_type(4))) float;
using frag16 = __attribute__((ext_vector_type(8))) short;

#define DI __device__ __forceinline__

constexpr int HID  = 2048;
constexpr int NH   = 16;
constexpr int HD   = 128;
constexpr int TT   = 4096;   // total tokens
constexpr int SEQ  = 2048;
constexpr int NQKV = 3 * HID; // 6144

DI short f2bf(float f) {
  unsigned u = __builtin_bit_cast(unsigned, f);
  unsigned r = (u + 0x7fffu + ((u >> 16) & 1u)) >> 16;
  return (short)r;
}
DI float bf2f(short s) {
  unsigned u = ((unsigned)(unsigned short)s) << 16;
  return __builtin_bit_cast(float, u);
}

// ---------------- elementwise f32 -> bf16 ----------------
struct alignas(8) S4h { short a, b, c, d; };

__global__ void conv_f32_bf16(const float* __restrict__ in, short* __restrict__ out) {
  int gid = blockIdx.x * 256 + threadIdx.x;
  const float4* in4 = (const float4*)in;
  float4 v = in4[gid];
  S4h o{f2bf(v.x), f2bf(v.y), f2bf(v.z), f2bf(v.w)};
  ((S4h*)out)[gid] = o;
}

// ---------------- transpose (+convert) : out[c][r] = in[r][c] ----------------
template <bool IN_F32>
__global__ void transpose_conv(const void* __restrict__ in_, short* __restrict__ out,
                               int ldin, int R) {
  __shared__ float t[64][65];
  const float* inf = (const float*)in_;
  const short* ins = (const short*)in_;
  int tid = threadIdx.x;
  int bx = blockIdx.x, by = blockIdx.y;
#pragma unroll
  for (int i = 0; i < 16; i++) {
    int idx = i * 256 + tid;
    int r = idx >> 6, c = idx & 63;
    size_t gi = (size_t)(by * 64 + r) * ldin + bx * 64 + c;
    t[r][c] = IN_F32 ? inf[gi] : bf2f(ins[gi]);
  }
  __syncthreads();
#pragma unroll
  for (int i = 0; i < 16; i++) {
    int idx = i * 256 + tid;
    int r = idx >> 6, c = idx & 63;
    out[(size_t)(bx * 64 + r) * R + by * 64 + c] = f2bf(t[c][r]);
  }
}

// ---------------- bf16 MFMA GEMM, B transposed (N x K), 128x128 tile ----------------
#define GLDS(src, dst)                                                     \
  __builtin_amdgcn_global_load_lds(                                        \
      (const __attribute__((address_space(1))) void*)(src),                \
      (__attribute__((address_space(3))) void*)(dst), 16, 0, 0)

template <bool ADD_BIAS, bool OUT_BF16>
__global__ __launch_bounds__(256, 2) void gemm_bt(
    const short* __restrict__ A, const short* __restrict__ Bt,
    const float* __restrict__ bias, void* __restrict__ Cout,
    int M, int N, int K) {
  __shared__ alignas(16) short Al[128 * 64];
  __shared__ alignas(16) short Bl[128 * 64];
  const int tid = threadIdx.x;
  const int wid = tid >> 6, lane = tid & 63;
  const int wr = wid >> 1, wc = wid & 1;
  const int l15 = lane & 15, lg = lane >> 4;
  const int row0 = blockIdx.y * 128, col0 = blockIdx.x * 128;
  const int lr8 = lane >> 3, l7 = lane & 7;

  f32x4 acc[4][4];
#pragma unroll
  for (int i = 0; i < 4; i++)
#pragma unroll
    for (int j = 0; j < 4; j++) acc[i][j] = {0.f, 0.f, 0.f, 0.f};

  for (int kt = 0; kt < K; kt += 64) {
    // stage 16KB A-tile + 16KB B-tile; LDS linear dest, inverse-swizzled source
#pragma unroll
    for (int c = 0; c < 4; c++) {
      int chunk = c * 4 + wid;             // 0..15 (1KB chunks)
      int r = chunk * 8 + lr8;             // LDS row 0..127
      int ke = (l7 * 8) ^ ((r & 7) * 8);   // element offset within 64-wide row
      GLDS(A + (size_t)(row0 + r) * K + kt + ke, Al + chunk * 512);
      GLDS(Bt + (size_t)(col0 + r) * K + kt + ke, Bl + chunk * 512);
    }
    __syncthreads();
#pragma unroll
    for (int kk = 0; kk < 2; kk++) {
      frag16 af[4], bfv[4];
#pragma unroll
      for (int ai = 0; ai < 4; ai++) {
        int r = wr * 64 + ai * 16 + l15;
        int k0 = kk * 32 + lg * 8;
        af[ai] = *(const frag16*)(Al + r * 64 + (k0 ^ ((r & 7) * 8)));
      }
#pragma unroll
      for (int bj = 0; bj < 4; bj++) {
        int r = wc * 64 + bj * 16 + l15;
        int k0 = kk * 32 + lg * 8;
        bfv[bj] = *(const frag16*)(Bl + r * 64 + (k0 ^ ((r & 7) * 8)));
      }
#pragma unroll
      for (int ai = 0; ai < 4; ai++)
#pragma unroll
        for (int bj = 0; bj < 4; bj++)
          acc[ai][bj] = __builtin_amdgcn_mfma_f32_16x16x32_bf16(
              af[ai], bfv[bj], acc[ai][bj], 0, 0, 0);
    }
    __syncthreads();
  }
#pragma unroll
  for (int ai = 0; ai < 4; ai++) {
#pragma unroll
    for (int bj = 0; bj < 4; bj++) {
      int row = row0 + wr * 64 + ai * 16 + lg * 4;
      int col = col0 + wc * 64 + bj * 16 + l15;
      float bv = 0.f;
      if (ADD_BIAS) bv = bias[col];
#pragma unroll
      for (int r = 0; r < 4; r++) {
        float v = acc[ai][bj][r] + bv;
        if (OUT_BF16)
          ((short*)Cout)[(size_t)(row + r) * N + col] = f2bf(v);
        else
          ((float*)Cout)[(size_t)(row + r) * N + col] = v;
      }
    }
  }
}

// ---------------- RoPE + cache scatter ----------------
__global__ void rope_scatter(const short* __restrict__ qkv, const float* __restrict__ cs,
                             const float* __restrict__ sn, const int* __restrict__ slots,
                             short* __restrict__ Qb, short* __restrict__ Kb,
                             float* __restrict__ kc, float* __restrict__ vc) {
  const int t = blockIdx.x;
  const int tid = threadIdx.x;
  const int slot = slots[t];
  const short* row = qkv + (size_t)t * NQKV;
  short* qo = Qb + (size_t)t * HID;
  short* ko = Kb + (size_t)t * HID;
  float* kco = kc + (size_t)slot * HID;
  float* vco = vc + (size_t)slot * HID;
#pragma unroll
  for (int i = 0; i < 4; i++) {
    int p = tid + i * 256;
    int h = p >> 6, d = p & 63;
    float c = cs[(size_t)t * 64 + d];
    float s = sn[(size_t)t * 64 + d];
    int c1 = h * 128 + d, c2 = c1 + 64;
    float q1 = bf2f(row[c1]), q2 = bf2f(row[c2]);
    qo[c1] = f2bf(q1 * c - q2 * s);
    qo[c2] = f2bf(q2 * c + q1 * s);
    float k1 = bf2f(row[HID + c1]), k2 = bf2f(row[HID + c2]);
    float ko1 = k1 * c - k2 * s, ko2 = k2 * c + k1 * s;
    ko[c1] = f2bf(ko1);
    ko[c2] = f2bf(ko2);
    kco[c1] = ko1;
    kco[c2] = ko2;
  }
#pragma unroll
  for (int i = 0; i < 8; i++) {
    int cidx = tid + i * 256;
    vco[cidx] = bf2f(row[2 * HID + cidx]);
  }
}

// ---------------- causal flash attention ----------------
// 1 wave = 16 q rows of one (b,h); KV tiles of 32; Vt is [h*HD+d][token]
__global__ __launch_bounds__(256, 2) void flash_attn(
    const short* __restrict__ Qb, const short* __restrict__ Kb,
    const short* __restrict__ Vt, short* __restrict__ attn) {
  __shared__ alignas(16) short plds[4][16][40];
  const int tid = threadIdx.x;
  const int wid = tid >> 6, lane = tid & 63;
  const int l15 = lane & 15, lg = lane >> 4;
  const int W = blockIdx.x * 4 + wid;
  const int qt = W & 127;
  const int bh = W >> 7;
  const int b = bh >> 4, h = bh & 15;
  short* pl = &plds[wid][0][0];

  frag16 qf[4];
  {
    const short* qp = Qb + (size_t)(b * SEQ + qt * 16 + l15) * HID + h * HD + lg * 8;
#pragma unroll
    for (int ds = 0; ds < 4; ds++) qf[ds] = *(const frag16*)(qp + ds * 32);
  }
  f32x4 o[8];
#pragma unroll
  for (int j = 0; j < 8; j++) o[j] = {0.f, 0.f, 0.f, 0.f};
  float mr[4] = {-1e30f, -1e30f, -1e30f, -1e30f};
  float lr[4] = {0.f, 0.f, 0.f, 0.f};
  const float scale = 0.08838834764831845f;
  const int ntf = qt >> 1;
  for (int ti = 0; ti <= ntf; ++ti) {
    const int kv0 = ti * 32;
    const bool maskt = (ti == ntf);
    f32x4 sa0 = {0.f, 0.f, 0.f, 0.f}, sa1 = {0.f, 0.f, 0.f, 0.f};
    {
      const short* kp = Kb + (size_t)(b * SEQ + kv0 + l15) * HID + h * HD + lg * 8;
#pragma unroll
      for (int ds = 0; ds < 4; ds++) {
        frag16 kf = *(const frag16*)(kp + ds * 32);
        sa0 = __builtin_amdgcn_mfma_f32_16x16x32_bf16(qf[ds], kf, sa0, 0, 0, 0);
      }
      const short* kp1 = kp + 16 * HID;
#pragma unroll
      for (int ds = 0; ds < 4; ds++) {
        frag16 kf = *(const frag16*)(kp1 + ds * 32);
        sa1 = __builtin_amdgcn_mfma_f32_16x16x32_bf16(qf[ds], kf, sa1, 0, 0, 0);
      }
    }
    float s0[4], s1[4], pm[4];
#pragma unroll
    for (int r = 0; r < 4; r++) {
      s0[r] = sa0[r] * scale;
      s1[r] = sa1[r] * scale;
      if (maskt) {
        int qi = qt * 16 + lg * 4 + r;
        if (kv0 + l15 > qi) s0[r] = -1e30f;
        if (kv0 + 16 + l15 > qi) s1[r] = -1e30f;
      }
      pm[r] = fmaxf(s0[r], s1[r]);
    }
#pragma unroll
    for (int m = 1; m < 16; m <<= 1) {
#pragma unroll
      for (int r = 0; r < 4; r++) pm[r] = fmaxf(pm[r], __shfl_xor(pm[r], m));
    }
    float fr[4], ps[4];
#pragma unroll
    for (int r = 0; r < 4; r++) {
      float mn = fmaxf(mr[r], pm[r]);
      fr[r] = __expf(mr[r] - mn);
      mr[r] = mn;
      float p0 = __expf(s0[r] - mn);
      float p1 = __expf(s1[r] - mn);
      ps[r] = p0 + p1;
      pl[(lg * 4 + r) * 40 + l15] = f2bf(p0);
      pl[(lg * 4 + r) * 40 + 16 + l15] = f2bf(p1);
    }
#pragma unroll
    for (int m = 1; m < 16; m <<= 1) {
#pragma unroll
      for (int r = 0; r < 4; r++) ps[r] += __shfl_xor(ps[r], m);
    }
#pragma unroll
    for (int r = 0; r < 4; r++) lr[r] = lr[r] * fr[r] + ps[r];
#pragma unroll
    for (int j = 0; j < 8; j++)
#pragma unroll
      for (int r = 0; r < 4; r++) o[j][r] *= fr[r];
    // P writes are cross-lane consumed: drain LDS before fragment read
    asm volatile("s_waitcnt lgkmcnt(0)" ::: "memory");
    frag16 pf = *(const frag16*)(pl + l15 * 40 + lg * 8);
    const short* vp = Vt + (size_t)(h * HD + l15) * TT + b * SEQ + kv0 + lg * 8;
#pragma unroll
    for (int j = 0; j < 8; j++) {
      frag16 vf = *(const frag16*)(vp + (size_t)j * 16 * TT);
      o[j] = __builtin_amdgcn_mfma_f32_16x16x32_bf16(pf, vf, o[j], 0, 0, 0);
    }
  }
  float inv[4];
#pragma unroll
  for (int r = 0; r < 4; r++) inv[r] = 1.f / lr[r];
  short* op = attn + (size_t)(b * SEQ + qt * 16 + lg * 4) * HID + h * HD + l15;
#pragma unroll
  for (int j = 0; j < 8; j++)
#pragma unroll
    for (int r = 0; r < 4; r++)
      op[(size_t)r * HID + j * 16] = f2bf(o[j][r] * inv[r]);
}

// ---------------- launcher ----------------
extern "C" void kernel_launch(void* const* d_in, const int* in_sizes, int n_in,
                              void* d_out, int out_size, void* d_ws, size_t ws_size,
                              hipStream_t stream) {
  const float* hidden = (const float*)d_in[0];
  const float* cosb   = (const float*)d_in[1];
  const float* sinb   = (const float*)d_in[2];
  const float* wqkv   = (const float*)d_in[3];
  const float* bqkv   = (const float*)d_in[4];
  const float* wo     = (const float*)d_in[5];
  const int*   slots  = (const int*)d_in[9];

  float* out = (float*)d_out;
  float* kc  = out + (size_t)TT * HID;
  float* vc  = kc + (size_t)TT * HID;

  short* ws    = (short*)d_ws;
  short* Abf   = ws;                       // 8,388,608 (reused as attn_bf16)
  short* Wqkvt = Abf + 8388608;            // 12,582,912
  short* Wot   = Wqkvt + 12582912;         // 4,194,304
  short* qkvb  = Wot + 4194304;            // 25,165,824
  short* Qb    = qkvb + 25165824;          // 8,388,608
  short* Kb    = Qb + 8388608;             // 8,388,608
  short* Vt    = Kb + 8388608;             // 8,388,608
  short* attnb = Abf;                      // reuse (A dead after GEMM1)

  conv_f32_bf16<<<8192, 256, 0, stream>>>(hidden, Abf);
  transpose_conv<true><<<dim3(96, 32), 256, 0, stream>>>(wqkv, Wqkvt, NQKV, HID);
  transpose_conv<true><<<dim3(32, 32), 256, 0, stream>>>(wo, Wot, HID, HID);
  gemm_bt<true, true><<<dim3(48, 32), 256, 0, stream>>>(Abf, Wqkvt, bqkv, qkvb,
                                                        TT, NQKV, HID);
  rope_scatter<<<TT, 256, 0, stream>>>(qkvb, cosb, sinb, slots, Qb, Kb, kc, vc);
  transpose_conv<false><<<dim3(32, 64), 256, 0, stream>>>(qkvb + 2 * HID, Vt, NQKV, TT);
  flash_attn<<<1024, 256, 0, stream>>>(Qb, Kb, Vt, attnb);
  gemm_bt<false, false><<<dim3(16, 32), 256, 0, stream>>>(attnb, Wot, nullptr, out,
                                                          TT, HID, HID);
}

// Round 2
// 363.806 us; speedup vs baseline: 1.7849x; 1.7849x over previous
//
#include <hip/hip_runtime.h>

using f32x4  = __attribute__((ext_vector_type(4))) float;
using frag16 = __attribute__((ext_vector_type(8))) short;

#define DI __device__ __forceinline__

constexpr int HID  = 2048;
constexpr int NH   = 16;
constexpr int HD   = 128;
constexpr int TT   = 4096;   // total tokens
constexpr int SEQ  = 2048;
constexpr int NQKV = 3 * HID; // 6144

DI short f2bf(float f) {
  unsigned u = __builtin_bit_cast(unsigned, f);
  unsigned r = (u + 0x7fffu + ((u >> 16) & 1u)) >> 16;
  return (short)r;
}
DI float bf2f(short s) {
  unsigned u = ((unsigned)(unsigned short)s) << 16;
  return __builtin_bit_cast(float, u);
}

// ---------------- elementwise f32 -> bf16 ----------------
struct alignas(8) S4h { short a, b, c, d; };

__global__ void conv_f32_bf16(const float* __restrict__ in, short* __restrict__ out) {
  int gid = blockIdx.x * 256 + threadIdx.x;
  const float4* in4 = (const float4*)in;
  float4 v = in4[gid];
  S4h o{f2bf(v.x), f2bf(v.y), f2bf(v.z), f2bf(v.w)};
  ((S4h*)out)[gid] = o;
}

// ---------------- transpose (+convert) : out[c][r] = in[r][c] ----------------
template <bool IN_F32>
__global__ void transpose_conv(const void* __restrict__ in_, short* __restrict__ out,
                               int ldin, int R) {
  __shared__ float t[64][65];
  const float* inf = (const float*)in_;
  const short* ins = (const short*)in_;
  int tid = threadIdx.x;
  int bx = blockIdx.x, by = blockIdx.y;
#pragma unroll
  for (int i = 0; i < 16; i++) {
    int idx = i * 256 + tid;
    int r = idx >> 6, c = idx & 63;
    size_t gi = (size_t)(by * 64 + r) * ldin + bx * 64 + c;
    t[r][c] = IN_F32 ? inf[gi] : bf2f(ins[gi]);
  }
  __syncthreads();
#pragma unroll
  for (int i = 0; i < 16; i++) {
    int idx = i * 256 + tid;
    int r = idx >> 6, c = idx & 63;
    out[(size_t)(bx * 64 + r) * R + by * 64 + c] = f2bf(t[c][r]);
  }
}

// ---------------- bf16 MFMA GEMM, B transposed (N x K), 128x128 tile ----------------
#define GLDS(src, dst)                                                     \
  __builtin_amdgcn_global_load_lds(                                        \
      (const __attribute__((address_space(1))) void*)(src),                \
      (__attribute__((address_space(3))) void*)(dst), 16, 0, 0)

template <bool ADD_BIAS, bool OUT_BF16>
__global__ __launch_bounds__(256, 2) void gemm_bt(
    const short* __restrict__ A, const short* __restrict__ Bt,
    const float* __restrict__ bias, void* __restrict__ Cout,
    int M, int N, int K) {
  __shared__ alignas(16) short Al[128 * 64];
  __shared__ alignas(16) short Bl[128 * 64];
  const int tid = threadIdx.x;
  const int wid = tid >> 6, lane = tid & 63;
  const int wr = wid >> 1, wc = wid & 1;
  const int l15 = lane & 15, lg = lane >> 4;
  const int row0 = blockIdx.y * 128, col0 = blockIdx.x * 128;
  const int lr8 = lane >> 3, l7 = lane & 7;

  f32x4 acc[4][4];
#pragma unroll
  for (int i = 0; i < 4; i++)
#pragma unroll
    for (int j = 0; j < 4; j++) acc[i][j] = {0.f, 0.f, 0.f, 0.f};

  for (int kt = 0; kt < K; kt += 64) {
#pragma unroll
    for (int c = 0; c < 4; c++) {
      int chunk = c * 4 + wid;             // 0..15 (1KB chunks)
      int r = chunk * 8 + lr8;             // LDS row 0..127
      int ke = (l7 * 8) ^ ((r & 7) * 8);   // element offset within 64-wide row
      GLDS(A + (size_t)(row0 + r) * K + kt + ke, Al + chunk * 512);
      GLDS(Bt + (size_t)(col0 + r) * K + kt + ke, Bl + chunk * 512);
    }
    __syncthreads();
#pragma unroll
    for (int kk = 0; kk < 2; kk++) {
      frag16 af[4], bfv[4];
#pragma unroll
      for (int ai = 0; ai < 4; ai++) {
        int r = wr * 64 + ai * 16 + l15;
        int k0 = kk * 32 + lg * 8;
        af[ai] = *(const frag16*)(Al + r * 64 + (k0 ^ ((r & 7) * 8)));
      }
#pragma unroll
      for (int bj = 0; bj < 4; bj++) {
        int r = wc * 64 + bj * 16 + l15;
        int k0 = kk * 32 + lg * 8;
        bfv[bj] = *(const frag16*)(Bl + r * 64 + (k0 ^ ((r & 7) * 8)));
      }
#pragma unroll
      for (int ai = 0; ai < 4; ai++)
#pragma unroll
        for (int bj = 0; bj < 4; bj++)
          acc[ai][bj] = __builtin_amdgcn_mfma_f32_16x16x32_bf16(
              af[ai], bfv[bj], acc[ai][bj], 0, 0, 0);
    }
    __syncthreads();
  }
#pragma unroll
  for (int ai = 0; ai < 4; ai++) {
#pragma unroll
    for (int bj = 0; bj < 4; bj++) {
      int row = row0 + wr * 64 + ai * 16 + lg * 4;
      int col = col0 + wc * 64 + bj * 16 + l15;
      float bv = 0.f;
      if (ADD_BIAS) bv = bias[col];
#pragma unroll
      for (int r = 0; r < 4; r++) {
        float v = acc[ai][bj][r] + bv;
        if (OUT_BF16)
          ((short*)Cout)[(size_t)(row + r) * N + col] = f2bf(v);
        else
          ((float*)Cout)[(size_t)(row + r) * N + col] = v;
      }
    }
  }
}

// ---------------- RoPE + cache scatter ----------------
__global__ void rope_scatter(const short* __restrict__ qkv, const float* __restrict__ cs,
                             const float* __restrict__ sn, const int* __restrict__ slots,
                             short* __restrict__ Qb, short* __restrict__ Kb,
                             float* __restrict__ kc, float* __restrict__ vc) {
  const int t = blockIdx.x;
  const int tid = threadIdx.x;
  const int slot = slots[t];
  const short* row = qkv + (size_t)t * NQKV;
  short* qo = Qb + (size_t)t * HID;
  short* ko = Kb + (size_t)t * HID;
  float* kco = kc + (size_t)slot * HID;
  float* vco = vc + (size_t)slot * HID;
#pragma unroll
  for (int i = 0; i < 4; i++) {
    int p = tid + i * 256;
    int h = p >> 6, d = p & 63;
    float c = cs[(size_t)t * 64 + d];
    float s = sn[(size_t)t * 64 + d];
    int c1 = h * 128 + d, c2 = c1 + 64;
    float q1 = bf2f(row[c1]), q2 = bf2f(row[c2]);
    qo[c1] = f2bf(q1 * c - q2 * s);
    qo[c2] = f2bf(q2 * c + q1 * s);
    float k1 = bf2f(row[HID + c1]), k2 = bf2f(row[HID + c2]);
    float ko1 = k1 * c - k2 * s, ko2 = k2 * c + k1 * s;
    ko[c1] = f2bf(ko1);
    ko[c2] = f2bf(ko2);
    kco[c1] = ko1;
    kco[c2] = ko2;
  }
#pragma unroll
  for (int i = 0; i < 8; i++) {
    int cidx = tid + i * 256;
    vco[cidx] = bf2f(row[2 * HID + cidx]);
  }
}

// ---------------- causal flash attention v2 ----------------
// Block = 4 waves = 128 q rows of one (b,h). Wave owns 32 rows (2 x 16-row tiles).
// KV tiles of 32 staged in LDS (double-buffered, global_load_lds w16, XOR swizzle).
__global__ __launch_bounds__(256, 2) void flash_attn2(
    const short* __restrict__ Qb, const short* __restrict__ Kb,
    const short* __restrict__ Vt, short* __restrict__ attn) {
  // K tile: [32 rows][128 d] bf16, 16B slots swizzled by (row&15)
  // V tile: [128 d][32 kv] bf16, 16B slots swizzled by (d&3)
  __shared__ alignas(16) short Klds[2][32 * 128];
  __shared__ alignas(16) short Vlds[2][128 * 32];
  __shared__ alignas(16) short plds[4][2][16 * 40];

  const int tid = threadIdx.x;
  const int w = tid >> 6, lane = tid & 63;
  const int l15 = lane & 15, lg = lane >> 4;
  const int bid = blockIdx.x;
  const int qb = 15 - (bid >> 5);          // heaviest q-blocks first
  const int bh = bid & 31;
  const int b = bh >> 4, h = bh & 15;
  const int q0 = qb * 128;
  const int qrow0 = q0 + w * 32;
  const int nt = qb * 4 + 4;

  // Q fragments: 2 row-tiles x 4 k-slices
  frag16 qf[2][4];
#pragma unroll
  for (int i = 0; i < 2; i++) {
    const short* qp = Qb + (size_t)(b * SEQ + qrow0 + i * 16 + l15) * HID + h * HD + lg * 8;
#pragma unroll
    for (int ds = 0; ds < 4; ds++) qf[i][ds] = *(const frag16*)(qp + ds * 32);
  }

  f32x4 o[2][8];
#pragma unroll
  for (int i = 0; i < 2; i++)
#pragma unroll
    for (int j = 0; j < 8; j++) o[i][j] = {0.f, 0.f, 0.f, 0.f};
  float mr[2][4], lr[2][4];
#pragma unroll
  for (int i = 0; i < 2; i++)
#pragma unroll
    for (int r = 0; r < 4; r++) { mr[i][r] = -1e30f; lr[i][r] = 0.f; }
  const float scale = 0.08838834764831845f;

  // ---- staging helper (as lambda to capture pointers) ----
  auto stage = [&](int kv0, int buf) {
#pragma unroll
    for (int ci = 0; ci < 2; ci++) {
      int e = ci * 256 + w * 64 + lane;
      int row = e >> 4, sp = e & 15;
      int ss = sp ^ (row & 15);
      GLDS(Kb + (size_t)(b * SEQ + kv0 + row) * HID + h * HD + ss * 8,
           &Klds[buf][(ci * 256 + w * 64) * 8]);
    }
#pragma unroll
    for (int ci = 0; ci < 2; ci++) {
      int e = ci * 256 + w * 64 + lane;
      int d = e >> 2, sp = e & 3;
      int ss = sp ^ (d & 3);
      GLDS(Vt + (size_t)(h * HD + d) * TT + b * SEQ + kv0 + ss * 8,
           &Vlds[buf][(ci * 256 + w * 64) * 8]);
    }
  };

  stage(0, 0);
  __syncthreads();

  int cur = 0;
  for (int t = 0; t < nt; t++) {
    const int kv0 = t * 32;
    if (t + 1 < nt) stage((t + 1) * 32, cur ^ 1);

    if (kv0 <= qrow0 + 31) {  // not fully masked for this wave
      const short* Kl = &Klds[cur][0];
      const short* Vl = &Vlds[cur][0];
      // QK^T: 8 ds_reads, 16 MFMA
      f32x4 sa[2][2];
#pragma unroll
      for (int i = 0; i < 2; i++)
#pragma unroll
        for (int j = 0; j < 2; j++) sa[i][j] = {0.f, 0.f, 0.f, 0.f};
#pragma unroll
      for (int j = 0; j < 2; j++) {
#pragma unroll
        for (int ds = 0; ds < 4; ds++) {
          int row = j * 16 + l15;
          int phys = (ds * 4 + lg) ^ l15;
          frag16 kf = *(const frag16*)(Kl + row * 128 + phys * 8);
          sa[0][j] = __builtin_amdgcn_mfma_f32_16x16x32_bf16(qf[0][ds], kf, sa[0][j], 0, 0, 0);
          sa[1][j] = __builtin_amdgcn_mfma_f32_16x16x32_bf16(qf[1][ds], kf, sa[1][j], 0, 0, 0);
        }
      }
      // online softmax per row-tile
      float fr[2][4];
#pragma unroll
      for (int i = 0; i < 2; i++) {
        const bool mk = (kv0 + 31 > qrow0 + i * 16);
        float s0[4], s1[4], pm[4];
#pragma unroll
        for (int r = 0; r < 4; r++) {
          s0[r] = sa[i][0][r] * scale;
          s1[r] = sa[i][1][r] * scale;
          if (mk) {
            int qi = qrow0 + i * 16 + lg * 4 + r;
            if (kv0 + l15 > qi) s0[r] = -1e30f;
            if (kv0 + 16 + l15 > qi) s1[r] = -1e30f;
          }
          pm[r] = fmaxf(s0[r], s1[r]);
        }
#pragma unroll
        for (int m = 1; m < 16; m <<= 1)
#pragma unroll
          for (int r = 0; r < 4; r++) pm[r] = fmaxf(pm[r], __shfl_xor(pm[r], m));
        float ps[4];
#pragma unroll
        for (int r = 0; r < 4; r++) {
          float mn = fmaxf(mr[i][r], pm[r]);
          fr[i][r] = __expf(mr[i][r] - mn);
          mr[i][r] = mn;
          float p0 = __expf(s0[r] - mn);
          float p1 = __expf(s1[r] - mn);
          ps[r] = p0 + p1;
          plds[w][i][(lg * 4 + r) * 40 + l15] = f2bf(p0);
          plds[w][i][(lg * 4 + r) * 40 + 16 + l15] = f2bf(p1);
        }
#pragma unroll
        for (int m = 1; m < 16; m <<= 1)
#pragma unroll
          for (int r = 0; r < 4; r++) ps[r] += __shfl_xor(ps[r], m);
#pragma unroll
        for (int r = 0; r < 4; r++) lr[i][r] = lr[i][r] * fr[i][r] + ps[r];
      }
      // rescale O
#pragma unroll
      for (int i = 0; i < 2; i++)
#pragma unroll
        for (int j = 0; j < 8; j++)
#pragma unroll
          for (int r = 0; r < 4; r++) o[i][j][r] *= fr[i][r];
      // P fragment (cross-lane via per-wave LDS)
      asm volatile("s_waitcnt lgkmcnt(0)" ::: "memory");
      frag16 pf[2];
#pragma unroll
      for (int i = 0; i < 2; i++)
        pf[i] = *(const frag16*)(&plds[w][i][l15 * 40 + lg * 8]);
      // PV: 8 ds_reads, 16 MFMA
#pragma unroll
      for (int j = 0; j < 8; j++) {
        int d = j * 16 + l15;
        int phys = lg ^ (d & 3);
        frag16 vf = *(const frag16*)(Vl + d * 32 + phys * 8);
        o[0][j] = __builtin_amdgcn_mfma_f32_16x16x32_bf16(pf[0], vf, o[0][j], 0, 0, 0);
        o[1][j] = __builtin_amdgcn_mfma_f32_16x16x32_bf16(pf[1], vf, o[1][j], 0, 0, 0);
      }
    }
    __syncthreads();
    cur ^= 1;
  }

#pragma unroll
  for (int i = 0; i < 2; i++) {
    float inv[4];
#pragma unroll
    for (int r = 0; r < 4; r++) inv[r] = 1.f / lr[i][r];
    short* op = attn + (size_t)(b * SEQ + qrow0 + i * 16 + lg * 4) * HID + h * HD + l15;
#pragma unroll
    for (int j = 0; j < 8; j++)
#pragma unroll
      for (int r = 0; r < 4; r++)
        op[(size_t)r * HID + j * 16] = f2bf(o[i][j][r] * inv[r]);
  }
}

// ---------------- launcher ----------------
extern "C" void kernel_launch(void* const* d_in, const int* in_sizes, int n_in,
                              void* d_out, int out_size, void* d_ws, size_t ws_size,
                              hipStream_t stream) {
  const float* hidden = (const float*)d_in[0];
  const float* cosb   = (const float*)d_in[1];
  const float* sinb   = (const float*)d_in[2];
  const float* wqkv   = (const float*)d_in[3];
  const float* bqkv   = (const float*)d_in[4];
  const float* wo     = (const float*)d_in[5];
  const int*   slots  = (const int*)d_in[9];

  float* out = (float*)d_out;
  float* kc  = out + (size_t)TT * HID;
  float* vc  = kc + (size_t)TT * HID;

  short* ws    = (short*)d_ws;
  short* Abf   = ws;                       // 8,388,608 (reused as attn_bf16)
  short* Wqkvt = Abf + 8388608;            // 12,582,912
  short* Wot   = Wqkvt + 12582912;         // 4,194,304
  short* qkvb  = Wot + 4194304;            // 25,165,824
  short* Qb    = qkvb + 25165824;          // 8,388,608
  short* Kb    = Qb + 8388608;             // 8,388,608
  short* Vt    = Kb + 8388608;             // 8,388,608
  short* attnb = Abf;                      // reuse (A dead after GEMM1)

  conv_f32_bf16<<<8192, 256, 0, stream>>>(hidden, Abf);
  transpose_conv<true><<<dim3(96, 32), 256, 0, stream>>>(wqkv, Wqkvt, NQKV, HID);
  transpose_conv<true><<<dim3(32, 32), 256, 0, stream>>>(wo, Wot, HID, HID);
  gemm_bt<true, true><<<dim3(48, 32), 256, 0, stream>>>(Abf, Wqkvt, bqkv, qkvb,
                                                        TT, NQKV, HID);
  rope_scatter<<<TT, 256, 0, stream>>>(qkvb, cosb, sinb, slots, Qb, Kb, kc, vc);
  transpose_conv<false><<<dim3(32, 64), 256, 0, stream>>>(qkvb + 2 * HID, Vt, NQKV, TT);
  flash_attn2<<<512, 256, 0, stream>>>(Qb, Kb, Vt, attnb);
  gemm_bt<false, false><<<dim3(16, 32), 256, 0, stream>>>(attnb, Wot, nullptr, out,
                                                          TT, HID, HID);
}

// Round 3
// 319.392 us; speedup vs baseline: 2.0331x; 1.1391x over previous
//
#include <hip/hip_runtime.h>

using f32x4  = __attribute__((ext_vector_type(4))) float;
using frag16 = __attribute__((ext_vector_type(8))) short;
using s16x4  = __attribute__((ext_vector_type(4))) short;
using s16x8  = __attribute__((ext_vector_type(8))) short;

#define DI __device__ __forceinline__

constexpr int HID  = 2048;
constexpr int NH   = 16;
constexpr int HD   = 128;
constexpr int TT   = 4096;   // total tokens
constexpr int SEQ  = 2048;
constexpr int NQKV = 3 * HID; // 6144

DI short f2bf(float f) {
  unsigned u = __builtin_bit_cast(unsigned, f);
  unsigned r = (u + 0x7fffu + ((u >> 16) & 1u)) >> 16;
  return (short)r;
}
DI float bf2f(short s) {
  unsigned u = ((unsigned)(unsigned short)s) << 16;
  return __builtin_bit_cast(float, u);
}

// ---------------- elementwise f32 -> bf16 ----------------
struct alignas(8) S4h { short a, b, c, d; };

__global__ void conv_f32_bf16(const float* __restrict__ in, short* __restrict__ out) {
  int gid = blockIdx.x * 256 + threadIdx.x;
  const float4* in4 = (const float4*)in;
  float4 v = in4[gid];
  S4h o{f2bf(v.x), f2bf(v.y), f2bf(v.z), f2bf(v.w)};
  ((S4h*)out)[gid] = o;
}

// ---------------- transpose (+convert) : out[c][r] = in[r][c] ----------------
template <bool IN_F32>
__global__ void transpose_conv(const void* __restrict__ in_, short* __restrict__ out,
                               int ldin, int R) {
  __shared__ float t[64][65];
  const float* inf = (const float*)in_;
  const short* ins = (const short*)in_;
  int tid = threadIdx.x;
  int bx = blockIdx.x, by = blockIdx.y;
#pragma unroll
  for (int i = 0; i < 16; i++) {
    int idx = i * 256 + tid;
    int r = idx >> 6, c = idx & 63;
    size_t gi = (size_t)(by * 64 + r) * ldin + bx * 64 + c;
    t[r][c] = IN_F32 ? inf[gi] : bf2f(ins[gi]);
  }
  __syncthreads();
#pragma unroll
  for (int i = 0; i < 16; i++) {
    int idx = i * 256 + tid;
    int r = idx >> 6, c = idx & 63;
    out[(size_t)(bx * 64 + r) * R + by * 64 + c] = f2bf(t[c][r]);
  }
}

// ---------------- bf16 MFMA GEMM, B transposed (N x K), 128x128 tile ----------------
#define GLDS(src, dst)                                                     \
  __builtin_amdgcn_global_load_lds(                                        \
      (const __attribute__((address_space(1))) void*)(src),                \
      (__attribute__((address_space(3))) void*)(dst), 16, 0, 0)

template <bool ADD_BIAS, bool OUT_BF16>
__global__ __launch_bounds__(256, 2) void gemm_bt(
    const short* __restrict__ A, const short* __restrict__ Bt,
    const float* __restrict__ bias, void* __restrict__ Cout,
    int M, int N, int K) {
  __shared__ alignas(16) short Al[128 * 64];
  __shared__ alignas(16) short Bl[128 * 64];
  const int tid = threadIdx.x;
  const int wid = tid >> 6, lane = tid & 63;
  const int wr = wid >> 1, wc = wid & 1;
  const int l15 = lane & 15, lg = lane >> 4;
  const int row0 = blockIdx.y * 128, col0 = blockIdx.x * 128;
  const int lr8 = lane >> 3, l7 = lane & 7;

  f32x4 acc[4][4];
#pragma unroll
  for (int i = 0; i < 4; i++)
#pragma unroll
    for (int j = 0; j < 4; j++) acc[i][j] = {0.f, 0.f, 0.f, 0.f};

  for (int kt = 0; kt < K; kt += 64) {
#pragma unroll
    for (int c = 0; c < 4; c++) {
      int chunk = c * 4 + wid;             // 0..15 (1KB chunks)
      int r = chunk * 8 + lr8;             // LDS row 0..127
      int ke = (l7 * 8) ^ ((r & 7) * 8);   // element offset within 64-wide row
      GLDS(A + (size_t)(row0 + r) * K + kt + ke, Al + chunk * 512);
      GLDS(Bt + (size_t)(col0 + r) * K + kt + ke, Bl + chunk * 512);
    }
    __syncthreads();
#pragma unroll
    for (int kk = 0; kk < 2; kk++) {
      frag16 af[4], bfv[4];
#pragma unroll
      for (int ai = 0; ai < 4; ai++) {
        int r = wr * 64 + ai * 16 + l15;
        int k0 = kk * 32 + lg * 8;
        af[ai] = *(const frag16*)(Al + r * 64 + (k0 ^ ((r & 7) * 8)));
      }
#pragma unroll
      for (int bj = 0; bj < 4; bj++) {
        int r = wc * 64 + bj * 16 + l15;
        int k0 = kk * 32 + lg * 8;
        bfv[bj] = *(const frag16*)(Bl + r * 64 + (k0 ^ ((r & 7) * 8)));
      }
#pragma unroll
      for (int ai = 0; ai < 4; ai++)
#pragma unroll
        for (int bj = 0; bj < 4; bj++)
          acc[ai][bj] = __builtin_amdgcn_mfma_f32_16x16x32_bf16(
              af[ai], bfv[bj], acc[ai][bj], 0, 0, 0);
    }
    __syncthreads();
  }
#pragma unroll
  for (int ai = 0; ai < 4; ai++) {
#pragma unroll
    for (int bj = 0; bj < 4; bj++) {
      int row = row0 + wr * 64 + ai * 16 + lg * 4;
      int col = col0 + wc * 64 + bj * 16 + l15;
      float bv = 0.f;
      if (ADD_BIAS) bv = bias[col];
#pragma unroll
      for (int r = 0; r < 4; r++) {
        float v = acc[ai][bj][r] + bv;
        if (OUT_BF16)
          ((short*)Cout)[(size_t)(row + r) * N + col] = f2bf(v);
        else
          ((float*)Cout)[(size_t)(row + r) * N + col] = v;
      }
    }
  }
}

// ---------------- RoPE + cache scatter (vectorized) ----------------
__global__ void rope_scatter(const short* __restrict__ qkv, const float* __restrict__ cs,
                             const float* __restrict__ sn, const int* __restrict__ slots,
                             short* __restrict__ Qb, short* __restrict__ Kb,
                             float* __restrict__ kc, float* __restrict__ vc) {
  const int t = blockIdx.x;
  const int tid = threadIdx.x;
  const int slot = slots[t];
  const short* row = qkv + (size_t)t * NQKV;
  short* qo = Qb + (size_t)t * HID;
  short* ko = Kb + (size_t)t * HID;
  float* kco = kc + (size_t)slot * HID;
  float* vco = vc + (size_t)slot * HID;

  const int h = tid >> 4, d0 = (tid & 15) * 4;
  const int c1 = h * 128 + d0, c2 = c1 + 64;
  float4 c4 = *(const float4*)(cs + (size_t)t * 64 + d0);
  float4 s4 = *(const float4*)(sn + (size_t)t * 64 + d0);
  float cc[4] = {c4.x, c4.y, c4.z, c4.w};
  float ssv[4] = {s4.x, s4.y, s4.z, s4.w};
  s16x4 q1 = *(const s16x4*)(row + c1);
  s16x4 q2 = *(const s16x4*)(row + c2);
  s16x4 k1 = *(const s16x4*)(row + HID + c1);
  s16x4 k2 = *(const s16x4*)(row + HID + c2);
  s16x4 qo1, qo2, ko1, ko2;
  float kcv1[4], kcv2[4];
#pragma unroll
  for (int r = 0; r < 4; r++) {
    float a = bf2f(q1[r]), b = bf2f(q2[r]);
    qo1[r] = f2bf(a * cc[r] - b * ssv[r]);
    qo2[r] = f2bf(b * cc[r] + a * ssv[r]);
    float ka = bf2f(k1[r]), kb = bf2f(k2[r]);
    float o1 = ka * cc[r] - kb * ssv[r];
    float o2 = kb * cc[r] + ka * ssv[r];
    ko1[r] = f2bf(o1);
    ko2[r] = f2bf(o2);
    kcv1[r] = o1;
    kcv2[r] = o2;
  }
  *(s16x4*)(qo + c1) = qo1;
  *(s16x4*)(qo + c2) = qo2;
  *(s16x4*)(ko + c1) = ko1;
  *(s16x4*)(ko + c2) = ko2;
  *(float4*)(kco + c1) = {kcv1[0], kcv1[1], kcv1[2], kcv1[3]};
  *(float4*)(kco + c2) = {kcv2[0], kcv2[1], kcv2[2], kcv2[3]};

  const int vi = tid * 8;
  s16x8 v8 = *(const s16x8*)(row + 2 * HID + vi);
  *(float4*)(vco + vi)     = {bf2f(v8[0]), bf2f(v8[1]), bf2f(v8[2]), bf2f(v8[3])};
  *(float4*)(vco + vi + 4) = {bf2f(v8[4]), bf2f(v8[5]), bf2f(v8[6]), bf2f(v8[7])};
}

// ---------------- causal flash attention v3 ----------------
// Block = 4 waves; wave owns 16 q rows. Block processes TWO 64-row strips
// (s and 31-s) -> uniform 66 KV-tiles/block across the whole grid.
// KV tiles of 32 in LDS (double-buffered, global_load_lds w16, XOR swizzle).
// Defer-max rescale (THR=8); row-sum l via MFMA with ones-vector.
__global__ __launch_bounds__(256, 2) void flash_attn3(
    const short* __restrict__ Qb, const short* __restrict__ Kb,
    const short* __restrict__ Vt, short* __restrict__ attn) {
  __shared__ alignas(16) short Klds[2][32 * 128];
  __shared__ alignas(16) short Vlds[2][128 * 32];
  __shared__ alignas(16) short plds[4][16 * 40];

  const int tid = threadIdx.x;
  const int w = tid >> 6, lane = tid & 63;
  const int l15 = lane & 15, lg = lane >> 4;
  const int bid = blockIdx.x;
  const int pr = bid >> 5;                 // 0..15 strip-pair index
  const int bh = bid & 31;
  const int b = bh >> 4, h = bh & 15;
  short* pl = &plds[w][0];
  const float scale = 0.08838834764831845f;

  frag16 ones;
#pragma unroll
  for (int j = 0; j < 8; j++) ones[j] = (short)0x3F80;

  auto stage = [&](int kv0, int buf) {
#pragma unroll
    for (int ci = 0; ci < 2; ci++) {
      int e = ci * 256 + w * 64 + lane;
      int row = e >> 4, sp = e & 15;
      int ss = sp ^ (row & 15);
      GLDS(Kb + (size_t)(b * SEQ + kv0 + row) * HID + h * HD + ss * 8,
           &Klds[buf][(ci * 256 + w * 64) * 8]);
    }
#pragma unroll
    for (int ci = 0; ci < 2; ci++) {
      int e = ci * 256 + w * 64 + lane;
      int d = e >> 2, sp = e & 3;
      int ss = sp ^ (d & 3);
      GLDS(Vt + (size_t)(h * HD + d) * TT + b * SEQ + kv0 + ss * 8,
           &Vlds[buf][(ci * 256 + w * 64) * 8]);
    }
  };

  const int strips[2] = {31 - pr, pr};
#pragma unroll 1
  for (int spi = 0; spi < 2; spi++) {
    const int s = strips[spi];
    const int qrow0 = s * 64 + w * 16;
    const int nt = 2 * s + 2;

    frag16 qf[4];
    {
      const short* qp = Qb + (size_t)(b * SEQ + qrow0 + l15) * HID + h * HD + lg * 8;
#pragma unroll
      for (int ds = 0; ds < 4; ds++) qf[ds] = *(const frag16*)(qp + ds * 32);
    }
    f32x4 o[8];
#pragma unroll
    for (int j = 0; j < 8; j++) o[j] = {0.f, 0.f, 0.f, 0.f};
    f32x4 la = {0.f, 0.f, 0.f, 0.f};
    float mr[4] = {-1e30f, -1e30f, -1e30f, -1e30f};

    stage(0, 0);
    __syncthreads();

    int cur = 0;
    for (int t = 0; t < nt; t++) {
      const int kv0 = t * 32;
      if (t + 1 < nt) stage(kv0 + 32, cur ^ 1);

      if (kv0 <= qrow0 + 15) {
        const short* Kl = &Klds[cur][0];
        const short* Vl = &Vlds[cur][0];
        f32x4 sa0 = {0.f, 0.f, 0.f, 0.f}, sa1 = {0.f, 0.f, 0.f, 0.f};
#pragma unroll
        for (int ds = 0; ds < 4; ds++) {
          int phys = (ds * 4 + lg) ^ l15;
          frag16 kf0 = *(const frag16*)(Kl + l15 * 128 + phys * 8);
          frag16 kf1 = *(const frag16*)(Kl + (16 + l15) * 128 + phys * 8);
          sa0 = __builtin_amdgcn_mfma_f32_16x16x32_bf16(qf[ds], kf0, sa0, 0, 0, 0);
          sa1 = __builtin_amdgcn_mfma_f32_16x16x32_bf16(qf[ds], kf1, sa1, 0, 0, 0);
        }
        float s0[4], s1[4], pm[4];
        const bool mk = (kv0 + 31 > qrow0);
#pragma unroll
        for (int r = 0; r < 4; r++) {
          s0[r] = sa0[r] * scale;
          s1[r] = sa1[r] * scale;
          if (mk) {
            int qi = qrow0 + lg * 4 + r;
            if (kv0 + l15 > qi) s0[r] = -1e30f;
            if (kv0 + 16 + l15 > qi) s1[r] = -1e30f;
          }
          pm[r] = fmaxf(s0[r], s1[r]);
        }
#pragma unroll
        for (int m = 1; m < 16; m <<= 1)
#pragma unroll
          for (int r = 0; r < 4; r++) pm[r] = fmaxf(pm[r], __shfl_xor(pm[r], m));
        // defer-max: rescale only when a row's max grew past THR=8
        bool need = false;
#pragma unroll
        for (int r = 0; r < 4; r++) need = need || (pm[r] > mr[r] + 8.f);
        if (__any(need)) {
#pragma unroll
          for (int r = 0; r < 4; r++) {
            float mn = fmaxf(mr[r], pm[r]);
            float fr = __expf(mr[r] - mn);
            mr[r] = mn;
            la[r] *= fr;
#pragma unroll
            for (int j = 0; j < 8; j++) o[j][r] *= fr;
          }
        }
#pragma unroll
        for (int r = 0; r < 4; r++) {
          float p0 = __expf(s0[r] - mr[r]);
          float p1 = __expf(s1[r] - mr[r]);
          pl[(lg * 4 + r) * 40 + l15] = f2bf(p0);
          pl[(lg * 4 + r) * 40 + 16 + l15] = f2bf(p1);
        }
        asm volatile("s_waitcnt lgkmcnt(0)" ::: "memory");
        frag16 pf = *(const frag16*)(pl + l15 * 40 + lg * 8);
        la = __builtin_amdgcn_mfma_f32_16x16x32_bf16(pf, ones, la, 0, 0, 0);
#pragma unroll
        for (int j = 0; j < 8; j++) {
          int d = j * 16 + l15;
          int phys = lg ^ (d & 3);
          frag16 vf = *(const frag16*)(Vl + d * 32 + phys * 8);
          o[j] = __builtin_amdgcn_mfma_f32_16x16x32_bf16(pf, vf, o[j], 0, 0, 0);
        }
      }
      __syncthreads();
      cur ^= 1;
    }

    float inv[4];
#pragma unroll
    for (int r = 0; r < 4; r++) inv[r] = 1.f / la[r];
    short* op = attn + (size_t)(b * SEQ + qrow0 + lg * 4) * HID + h * HD + l15;
#pragma unroll
    for (int j = 0; j < 8; j++)
#pragma unroll
      for (int r = 0; r < 4; r++)
        op[(size_t)r * HID + j * 16] = f2bf(o[j][r] * inv[r]);
    __syncthreads();
  }
}

// ---------------- launcher ----------------
extern "C" void kernel_launch(void* const* d_in, const int* in_sizes, int n_in,
                              void* d_out, int out_size, void* d_ws, size_t ws_size,
                              hipStream_t stream) {
  const float* hidden = (const float*)d_in[0];
  const float* cosb   = (const float*)d_in[1];
  const float* sinb   = (const float*)d_in[2];
  const float* wqkv   = (const float*)d_in[3];
  const float* bqkv   = (const float*)d_in[4];
  const float* wo     = (const float*)d_in[5];
  const int*   slots  = (const int*)d_in[9];

  float* out = (float*)d_out;
  float* kc  = out + (size_t)TT * HID;
  float* vc  = kc + (size_t)TT * HID;

  short* ws    = (short*)d_ws;
  short* Abf   = ws;                       // 8,388,608 (reused as attn_bf16)
  short* Wqkvt = Abf + 8388608;            // 12,582,912
  short* Wot   = Wqkvt + 12582912;         // 4,194,304
  short* qkvb  = Wot + 4194304;            // 25,165,824
  short* Qb    = qkvb + 25165824;          // 8,388,608
  short* Kb    = Qb + 8388608;             // 8,388,608
  short* Vt    = Kb + 8388608;             // 8,388,608
  short* attnb = Abf;                      // reuse (A dead after GEMM1)

  conv_f32_bf16<<<8192, 256, 0, stream>>>(hidden, Abf);
  transpose_conv<true><<<dim3(96, 32), 256, 0, stream>>>(wqkv, Wqkvt, NQKV, HID);
  transpose_conv<true><<<dim3(32, 32), 256, 0, stream>>>(wo, Wot, HID, HID);
  gemm_bt<true, true><<<dim3(48, 32), 256, 0, stream>>>(Abf, Wqkvt, bqkv, qkvb,
                                                        TT, NQKV, HID);
  rope_scatter<<<TT, 256, 0, stream>>>(qkvb, cosb, sinb, slots, Qb, Kb, kc, vc);
  transpose_conv<false><<<dim3(32, 64), 256, 0, stream>>>(qkvb + 2 * HID, Vt, NQKV, TT);
  flash_attn3<<<512, 256, 0, stream>>>(Qb, Kb, Vt, attnb);
  gemm_bt<false, false><<<dim3(16, 32), 256, 0, stream>>>(attnb, Wot, nullptr, out,
                                                          TT, HID, HID);
}

// Round 4
// 297.859 us; speedup vs baseline: 2.1801x; 1.0723x over previous
//
#include <hip/hip_runtime.h>

using f32x4  = __attribute__((ext_vector_type(4))) float;
using frag16 = __attribute__((ext_vector_type(8))) short;
using s16x4  = __attribute__((ext_vector_type(4))) short;
using s16x8  = __attribute__((ext_vector_type(8))) short;
using u32x4  = __attribute__((ext_vector_type(4))) unsigned;

#define DI __device__ __forceinline__

constexpr int HID  = 2048;
constexpr int NH   = 16;
constexpr int HD   = 128;
constexpr int TT   = 4096;   // total tokens
constexpr int SEQ  = 2048;
constexpr int NQKV = 3 * HID; // 6144

DI short f2bf(float f) {
  unsigned u = __builtin_bit_cast(unsigned, f);
  unsigned r = (u + 0x7fffu + ((u >> 16) & 1u)) >> 16;
  return (short)r;
}
DI float bf2f(short s) {
  unsigned u = ((unsigned)(unsigned short)s) << 16;
  return __builtin_bit_cast(float, u);
}
DI unsigned cvtpk(float lo, float hi) {
  unsigned r;
  asm("v_cvt_pk_bf16_f32 %0, %1, %2" : "=v"(r) : "v"(lo), "v"(hi));
  return r;
}

// ---------------- elementwise f32 -> bf16 ----------------
struct alignas(8) S4h { short a, b, c, d; };

__global__ void conv_f32_bf16(const float* __restrict__ in, short* __restrict__ out) {
  int gid = blockIdx.x * 256 + threadIdx.x;
  const float4* in4 = (const float4*)in;
  float4 v = in4[gid];
  S4h o{f2bf(v.x), f2bf(v.y), f2bf(v.z), f2bf(v.w)};
  ((S4h*)out)[gid] = o;
}

// ---------------- transpose (+convert) : out[c][r] = in[r][c] ----------------
// PERM: permute token index within 64-groups: dest col' holds source token
// invperm(c') = 16*(c'&3) + 4*(c'>>4) + ((c'>>2)&3)  (for attention kv' order)
template <bool IN_F32, bool PERM>
__global__ void transpose_conv(const void* __restrict__ in_, short* __restrict__ out,
                               int ldin, int R) {
  __shared__ float t[64][65];
  const float* inf = (const float*)in_;
  const short* ins = (const short*)in_;
  int tid = threadIdx.x;
  int bx = blockIdx.x, by = blockIdx.y;
#pragma unroll
  for (int i = 0; i < 16; i++) {
    int idx = i * 256 + tid;
    int r = idx >> 6, c = idx & 63;
    size_t gi = (size_t)(by * 64 + r) * ldin + bx * 64 + c;
    t[r][c] = IN_F32 ? inf[gi] : bf2f(ins[gi]);
  }
  __syncthreads();
#pragma unroll
  for (int i = 0; i < 16; i++) {
    int idx = i * 256 + tid;
    int r = idx >> 6, c = idx & 63;
    int cs = PERM ? (16 * (c & 3) + 4 * (c >> 4) + ((c >> 2) & 3)) : c;
    out[(size_t)(bx * 64 + r) * R + by * 64 + c] = f2bf(t[cs][r]);
  }
}

// ---------------- bf16 MFMA GEMM, B transposed (N x K), 128x128 tile ----------------
#define GLDS(src, dst)                                                     \
  __builtin_amdgcn_global_load_lds(                                        \
      (const __attribute__((address_space(1))) void*)(src),                \
      (__attribute__((address_space(3))) void*)(dst), 16, 0, 0)

template <bool ADD_BIAS, bool OUT_BF16>
__global__ __launch_bounds__(256, 2) void gemm_bt(
    const short* __restrict__ A, const short* __restrict__ Bt,
    const float* __restrict__ bias, void* __restrict__ Cout,
    int M, int N, int K) {
  __shared__ alignas(16) short Al[128 * 64];
  __shared__ alignas(16) short Bl[128 * 64];
  const int tid = threadIdx.x;
  const int wid = tid >> 6, lane = tid & 63;
  const int wr = wid >> 1, wc = wid & 1;
  const int l15 = lane & 15, lg = lane >> 4;
  // XCD-aware swizzle (grid counts are multiples of 8)
  const int gx = gridDim.x;
  const int id = blockIdx.y * gx + blockIdx.x;
  const int nwg = gx * gridDim.y;
  const int swz = (id & 7) * (nwg >> 3) + (id >> 3);
  const int row0 = (swz / gx) * 128, col0 = (swz % gx) * 128;
  const int lr8 = lane >> 3, l7 = lane & 7;

  f32x4 acc[4][4];
#pragma unroll
  for (int i = 0; i < 4; i++)
#pragma unroll
    for (int j = 0; j < 4; j++) acc[i][j] = {0.f, 0.f, 0.f, 0.f};

  for (int kt = 0; kt < K; kt += 64) {
#pragma unroll
    for (int c = 0; c < 4; c++) {
      int chunk = c * 4 + wid;             // 0..15 (1KB chunks)
      int r = chunk * 8 + lr8;             // LDS row 0..127
      int ke = (l7 * 8) ^ ((r & 7) * 8);   // element offset within 64-wide row
      GLDS(A + (size_t)(row0 + r) * K + kt + ke, Al + chunk * 512);
      GLDS(Bt + (size_t)(col0 + r) * K + kt + ke, Bl + chunk * 512);
    }
    __syncthreads();
#pragma unroll
    for (int kk = 0; kk < 2; kk++) {
      frag16 af[4], bfv[4];
#pragma unroll
      for (int ai = 0; ai < 4; ai++) {
        int r = wr * 64 + ai * 16 + l15;
        int k0 = kk * 32 + lg * 8;
        af[ai] = *(const frag16*)(Al + r * 64 + (k0 ^ ((r & 7) * 8)));
      }
#pragma unroll
      for (int bj = 0; bj < 4; bj++) {
        int r = wc * 64 + bj * 16 + l15;
        int k0 = kk * 32 + lg * 8;
        bfv[bj] = *(const frag16*)(Bl + r * 64 + (k0 ^ ((r & 7) * 8)));
      }
#pragma unroll
      for (int ai = 0; ai < 4; ai++)
#pragma unroll
        for (int bj = 0; bj < 4; bj++)
          acc[ai][bj] = __builtin_amdgcn_mfma_f32_16x16x32_bf16(
              af[ai], bfv[bj], acc[ai][bj], 0, 0, 0);
    }
    __syncthreads();
  }
#pragma unroll
  for (int ai = 0; ai < 4; ai++) {
#pragma unroll
    for (int bj = 0; bj < 4; bj++) {
      int row = row0 + wr * 64 + ai * 16 + lg * 4;
      int col = col0 + wc * 64 + bj * 16 + l15;
      float bv = 0.f;
      if (ADD_BIAS) bv = bias[col];
#pragma unroll
      for (int r = 0; r < 4; r++) {
        float v = acc[ai][bj][r] + bv;
        if (OUT_BF16)
          ((short*)Cout)[(size_t)(row + r) * N + col] = f2bf(v);
        else
          ((float*)Cout)[(size_t)(row + r) * N + col] = v;
      }
    }
  }
}

// ---------------- RoPE + cache scatter (vectorized, Q pre-scaled) ----------------
__global__ void rope_scatter(const short* __restrict__ qkv, const float* __restrict__ cs,
                             const float* __restrict__ sn, const int* __restrict__ slots,
                             short* __restrict__ Qb, short* __restrict__ Kb,
                             float* __restrict__ kc, float* __restrict__ vc) {
  const float SCL = 0.08838834764831845f * 1.4426950408889634f; // scale * log2e
  const int t = blockIdx.x;
  const int tid = threadIdx.x;
  const int slot = slots[t];
  const short* row = qkv + (size_t)t * NQKV;
  short* qo = Qb + (size_t)t * HID;
  short* ko = Kb + (size_t)t * HID;
  float* kco = kc + (size_t)slot * HID;
  float* vco = vc + (size_t)slot * HID;

  const int h = tid >> 4, d0 = (tid & 15) * 4;
  const int c1 = h * 128 + d0, c2 = c1 + 64;
  float4 c4 = *(const float4*)(cs + (size_t)t * 64 + d0);
  float4 s4 = *(const float4*)(sn + (size_t)t * 64 + d0);
  float cc[4] = {c4.x, c4.y, c4.z, c4.w};
  float ssv[4] = {s4.x, s4.y, s4.z, s4.w};
  s16x4 q1 = *(const s16x4*)(row + c1);
  s16x4 q2 = *(const s16x4*)(row + c2);
  s16x4 k1 = *(const s16x4*)(row + HID + c1);
  s16x4 k2 = *(const s16x4*)(row + HID + c2);
  s16x4 qo1, qo2, ko1, ko2;
  float kcv1[4], kcv2[4];
#pragma unroll
  for (int r = 0; r < 4; r++) {
    float a = bf2f(q1[r]), b = bf2f(q2[r]);
    qo1[r] = f2bf((a * cc[r] - b * ssv[r]) * SCL);
    qo2[r] = f2bf((b * cc[r] + a * ssv[r]) * SCL);
    float ka = bf2f(k1[r]), kb = bf2f(k2[r]);
    float o1 = ka * cc[r] - kb * ssv[r];
    float o2 = kb * cc[r] + ka * ssv[r];
    ko1[r] = f2bf(o1);
    ko2[r] = f2bf(o2);
    kcv1[r] = o1;
    kcv2[r] = o2;
  }
  *(s16x4*)(qo + c1) = qo1;
  *(s16x4*)(qo + c2) = qo2;
  *(s16x4*)(ko + c1) = ko1;
  *(s16x4*)(ko + c2) = ko2;
  *(float4*)(kco + c1) = {kcv1[0], kcv1[1], kcv1[2], kcv1[3]};
  *(float4*)(kco + c2) = {kcv2[0], kcv2[1], kcv2[2], kcv2[3]};

  const int vi = tid * 8;
  s16x8 v8 = *(const s16x8*)(row + 2 * HID + vi);
  *(float4*)(vco + vi)     = {bf2f(v8[0]), bf2f(v8[1]), bf2f(v8[2]), bf2f(v8[3])};
  *(float4*)(vco + vi + 4) = {bf2f(v8[4]), bf2f(v8[5]), bf2f(v8[6]), bf2f(v8[7])};
}

// ---------------- causal flash attention v4 ----------------
// Swapped QK^T: sa = mfma(K, Q) -> q on lane&15 (one q/lane, kv in-lane).
// Block = 4 waves x 16 q rows = 64-row strip; strips paired (s, 31-s).
// KVBLK=64, double-buffered LDS. P packed via cvt_pk into kv'-interleaved
// layout matching pre-permuted Vt. Row-sum via ones-MFMA. Defer-max (THR=8,
// log2 domain; scale*log2e pre-folded into Q).
__global__ __launch_bounds__(256, 2) void flash_attn4(
    const short* __restrict__ Qb, const short* __restrict__ Kb,
    const short* __restrict__ Vt, short* __restrict__ attn) {
  __shared__ alignas(16) short Klds[2][64 * 128];
  __shared__ alignas(16) short Vlds[2][128 * 64];
  __shared__ alignas(16) short plds[4][16 * 72];   // stride 72 shorts = 144B

  const int tid = threadIdx.x;
  const int w = tid >> 6, lane = tid & 63;
  const int l15 = lane & 15, lg = lane >> 4;
  const int bid = blockIdx.x;
  const int pr = bid >> 5;                 // 0..15 strip-pair index
  const int bh = bid & 31;
  const int b = bh >> 4, h = bh & 15;
  short* pl = &plds[w][0];

  frag16 ones;
#pragma unroll
  for (int j = 0; j < 8; j++) ones[j] = (short)0x3F80;

  auto stage = [&](int kv0, int buf) {
#pragma unroll
    for (int ci = 0; ci < 4; ci++) {
      int cc = w * 4 + ci;                 // 0..15
      int krow = cc * 4 + (lane >> 4);
      int ksp = lane & 15;
      int kss = ksp ^ (krow & 15);
      GLDS(Kb + (size_t)(b * SEQ + kv0 + krow) * HID + h * HD + kss * 8,
           Klds[buf] + cc * 512);
      int vd = cc * 8 + (lane >> 3);
      int vsp = lane & 7;
      int vss = vsp ^ (vd & 7);
      GLDS(Vt + (size_t)(h * HD + vd) * TT + b * SEQ + kv0 + vss * 8,
           Vlds[buf] + cc * 512);
    }
  };

  const int strips[2] = {31 - pr, pr};
#pragma unroll 1
  for (int spi = 0; spi < 2; spi++) {
    const int s = strips[spi];
    const int qrow0 = s * 64 + w * 16;
    const int nt = s + 1;

    frag16 qf[4];
    {
      const short* qp = Qb + (size_t)(b * SEQ + qrow0 + l15) * HID + h * HD + lg * 8;
#pragma unroll
      for (int ds = 0; ds < 4; ds++) qf[ds] = *(const frag16*)(qp + ds * 32);
    }
    f32x4 o[8];
#pragma unroll
    for (int j = 0; j < 8; j++) o[j] = {0.f, 0.f, 0.f, 0.f};
    f32x4 la = {0.f, 0.f, 0.f, 0.f};
    float mr = -1e30f;                     // per-lane: q = qrow0 + l15

    stage(0, 0);
    __syncthreads();

    int cur = 0;
    for (int t = 0; t < nt; t++) {
      const int kv0 = t * 64;
      if (t + 1 < nt) stage(kv0 + 64, cur ^ 1);

      const short* Kl = &Klds[cur][0];
      const short* Vl = &Vlds[cur][0];
      // QK^T swapped: sa[f] rows = kv (f*16 + lg*4 + r), col = q = l15
      f32x4 sa[4];
#pragma unroll
      for (int f = 0; f < 4; f++) sa[f] = {0.f, 0.f, 0.f, 0.f};
#pragma unroll
      for (int ds = 0; ds < 4; ds++) {
        int phys = (ds * 4 + lg) ^ l15;
#pragma unroll
        for (int f = 0; f < 4; f++) {
          frag16 kf = *(const frag16*)(Kl + (f * 16 + l15) * 128 + phys * 8);
          sa[f] = __builtin_amdgcn_mfma_f32_16x16x32_bf16(kf, qf[ds], sa[f], 0, 0, 0);
        }
      }
      // mask (diagonal tile only)
      if (kv0 + 63 > qrow0) {
        int ql = 16 * w + l15;
#pragma unroll
        for (int f = 0; f < 4; f++)
#pragma unroll
          for (int r = 0; r < 4; r++)
            if (f * 16 + lg * 4 + r > ql) sa[f][r] = -1e30f;
      }
      // in-lane row-max over 16 values, then 2 cross hops
      float pm = sa[0][0];
#pragma unroll
      for (int f = 0; f < 4; f++)
#pragma unroll
        for (int r = 0; r < 4; r++) pm = fmaxf(pm, sa[f][r]);
      pm = fmaxf(pm, __shfl_xor(pm, 16));
      pm = fmaxf(pm, __shfl_xor(pm, 32));
      // defer-max (log2 domain, THR=8)
      if (__any(pm > mr + 8.f)) {
        float mn = fmaxf(mr, pm);
        float frl = exp2f(mr - mn);
        mr = mn;
        float fr4[4];
#pragma unroll
        for (int r = 0; r < 4; r++)
          fr4[r] = __shfl(frl, lg * 16 + lg * 4 + r);
#pragma unroll
        for (int r = 0; r < 4; r++) {
          la[r] *= fr4[r];
#pragma unroll
          for (int j = 0; j < 8; j++) o[j][r] *= fr4[r];
        }
      }
      // P = exp2(s - m), pack into kv'-interleaved LDS row (q = l15)
      float pe[4][4];
#pragma unroll
      for (int f = 0; f < 4; f++)
#pragma unroll
        for (int r = 0; r < 4; r++) pe[f][r] = exp2f(sa[f][r] - mr);
      unsigned wv[8];
#pragma unroll
      for (int r = 0; r < 4; r++) {
        wv[2 * r]     = cvtpk(pe[0][r], pe[1][r]);
        wv[2 * r + 1] = cvtpk(pe[2][r], pe[3][r]);
      }
      {
        u32x4* pb = (u32x4*)(pl + l15 * 72 + lg * 16);
        pb[0] = {wv[0], wv[1], wv[2], wv[3]};
        pb[1] = {wv[4], wv[5], wv[6], wv[7]};
      }
      asm volatile("s_waitcnt lgkmcnt(0)" ::: "memory");
      frag16 pf0 = *(const frag16*)(pl + l15 * 72 + lg * 8);
      frag16 pf1 = *(const frag16*)(pl + l15 * 72 + 32 + lg * 8);
      la = __builtin_amdgcn_mfma_f32_16x16x32_bf16(pf0, ones, la, 0, 0, 0);
      la = __builtin_amdgcn_mfma_f32_16x16x32_bf16(pf1, ones, la, 0, 0, 0);
#pragma unroll
      for (int j = 0; j < 8; j++) {
        int d = j * 16 + l15;
        int p0 = lg ^ (d & 7);
        int p1 = (4 + lg) ^ (d & 7);
        frag16 vf0 = *(const frag16*)(Vl + d * 64 + p0 * 8);
        frag16 vf1 = *(const frag16*)(Vl + d * 64 + p1 * 8);
        o[j] = __builtin_amdgcn_mfma_f32_16x16x32_bf16(pf0, vf0, o[j], 0, 0, 0);
        o[j] = __builtin_amdgcn_mfma_f32_16x16x32_bf16(pf1, vf1, o[j], 0, 0, 0);
      }
      __syncthreads();
      cur ^= 1;
    }

    float inv[4];
#pragma unroll
    for (int r = 0; r < 4; r++) inv[r] = 1.f / la[r];
    short* op = attn + (size_t)(b * SEQ + qrow0 + lg * 4) * HID + h * HD + l15;
#pragma unroll
    for (int j = 0; j < 8; j++)
#pragma unroll
      for (int r = 0; r < 4; r++)
        op[(size_t)r * HID + j * 16] = f2bf(o[j][r] * inv[r]);
  }
}

// ---------------- launcher ----------------
extern "C" void kernel_launch(void* const* d_in, const int* in_sizes, int n_in,
                              void* d_out, int out_size, void* d_ws, size_t ws_size,
                              hipStream_t stream) {
  const float* hidden = (const float*)d_in[0];
  const float* cosb   = (const float*)d_in[1];
  const float* sinb   = (const float*)d_in[2];
  const float* wqkv   = (const float*)d_in[3];
  const float* bqkv   = (const float*)d_in[4];
  const float* wo     = (const float*)d_in[5];
  const int*   slots  = (const int*)d_in[9];

  float* out = (float*)d_out;
  float* kc  = out + (size_t)TT * HID;
  float* vc  = kc + (size_t)TT * HID;

  short* ws    = (short*)d_ws;
  short* Abf   = ws;                       // 8,388,608 (reused as attn_bf16)
  short* Wqkvt = Abf + 8388608;            // 12,582,912
  short* Wot   = Wqkvt + 12582912;         // 4,194,304
  short* qkvb  = Wot + 4194304;            // 25,165,824
  short* Qb    = qkvb + 25165824;          // 8,388,608
  short* Kb    = Qb + 8388608;             // 8,388,608
  short* Vt    = Kb + 8388608;             // 8,388,608
  short* attnb = Abf;                      // reuse (A dead after GEMM1)

  conv_f32_bf16<<<8192, 256, 0, stream>>>(hidden, Abf);
  transpose_conv<true, false><<<dim3(96, 32), 256, 0, stream>>>(wqkv, Wqkvt, NQKV, HID);
  transpose_conv<true, false><<<dim3(32, 32), 256, 0, stream>>>(wo, Wot, HID, HID);
  gemm_bt<true, true><<<dim3(48, 32), 256, 0, stream>>>(Abf, Wqkvt, bqkv, qkvb,
                                                        TT, NQKV, HID);
  rope_scatter<<<TT, 256, 0, stream>>>(qkvb, cosb, sinb, slots, Qb, Kb, kc, vc);
  transpose_conv<false, true><<<dim3(32, 64), 256, 0, stream>>>(qkvb + 2 * HID, Vt, NQKV, TT);
  flash_attn4<<<512, 256, 0, stream>>>(Qb, Kb, Vt, attnb);
  gemm_bt<false, false><<<dim3(16, 32), 256, 0, stream>>>(attnb, Wot, nullptr, out,
                                                          TT, HID, HID);
}